// Round 10
// baseline (2081.419 us; speedup 1.0000x reference)
//
#include <hip/hip_runtime.h>

// MyRnn: 2-layer SimpleRNN, B=1024 T=80 U=1024 E=100. f32 I/O, f16 MFMA compute.
// v9b (resubmit — R9 was a GPU-acquisition infra failure; + one audit fix:
// sched_barrier(0) after the consumer's PS vmcnt(0) drain, rule-18 hazard).
// Staging-INTENSITY restructure: all gfx950 GEMMs stage at ~55-60 GB/s/CU;
// v7 staged 800 KB/CU/iter at intensity 32 -> 14.5 us/iter floor = the wall.
//   - layer1: 128x128 tiles (intensity 64), K SPLIT BY SOURCE across a block
//     pair (s0 = h0@W1x, s1 = h1@W1h). s1 publishes f32 partials via WT sc0sc1
//     + epoch flag; s0 polls, bypass-reads, adds, tanh, WT-stores h1.
//   - layer0: 128x64 tiles un-split (K=1152: EMBP 2 chunks + h0 16 chunks).
//   - 256 blocks x 512 threads (8 waves), 1 block/CU (128 KB LDS), KC=64,
//     4-buffer 3-ahead counted-vmcnt pipeline (v8 geometry: 0 bank conflicts).
// Coherence machinery unchanged from v7 (WT sc0sc1 h-stores, bypass gl_lds
// h-loads, relaxed hierarchical grid barrier).

typedef _Float16 h8v __attribute__((ext_vector_type(8)));
typedef float    f4v __attribute__((ext_vector_type(4)));
typedef unsigned int u4v __attribute__((ext_vector_type(4)));

#define UNITS 1024
#define SEQ   80
#define EMBD  100
#define EPAD  128
#define KC    64
#define GRID  256

__device__ __forceinline__ float tanh_fast(float x) {
    x = fminf(15.f, fmaxf(-15.f, x));   // also scrubs NaN
    float e = __expf(2.f * x);
    return (e - 1.f) / (e + 1.f);
}

// cacheable global->LDS (weights, EMBP): L1/L2-resident across iterations
__device__ __forceinline__ void gl_lds16_c(const _Float16* g, _Float16* l) {
    __builtin_amdgcn_global_load_lds(
        (const __attribute__((address_space(1))) void*)g,
        (__attribute__((address_space(3))) void*)l, 16, 0, 0);
}
// device-coherent bypass global->LDS (h-state): aux = sc0|sc1 = 0x11
__device__ __forceinline__ void gl_lds16_v(const _Float16* g, _Float16* l) {
    __builtin_amdgcn_global_load_lds(
        (const __attribute__((address_space(1))) void*)g,
        (__attribute__((address_space(3))) void*)l, 16, 0, 0x11);
}
// write-through device-coherent 2B store (h-state)
__device__ __forceinline__ void st2_wt(_Float16* p, float v) {
    _Float16 h = (_Float16)v;
    unsigned int uv = (unsigned int)__builtin_bit_cast(unsigned short, h);
    asm volatile("global_store_short %0, %1, off sc0 sc1" :: "v"(p), "v"(uv) : "memory");
}
// write-through device-coherent 4B store (partial sums)
__device__ __forceinline__ void st4_wt(float* p, float v) {
    asm volatile("global_store_dword %0, %1, off sc0 sc1" :: "v"(p), "v"(v) : "memory");
}
// device-coherent 16B load (tail h read)
__device__ __forceinline__ u4v ld16_v(const void* p) {
    u4v r;
    asm volatile("global_load_dwordx4 %0, %1, off sc0 sc1\n\ts_waitcnt vmcnt(0)"
                 : "=v"(r) : "v"(p) : "memory");
    return r;
}
// write-through 16B store (h zero-init must land at coherent point)
__device__ __forceinline__ void st16_wt(void* p, u4v v) {
    asm volatile("global_store_dwordx4 %0, %1, off sc0 sc1" :: "v"(p), "v"(v) : "memory");
}

// embp[r][k] = k<100 ? (f16)emb[r][k] : 0   (10000 x 128)
__global__ void embp_kernel(const float* __restrict__ emb, _Float16* __restrict__ embp) {
    int r = blockIdx.x, k = threadIdx.x;
    embp[r * EPAD + k] = (k < EMBD) ? (_Float16)emb[r * EMBD + k] : (_Float16)0.f;
}

// wt[n][kp] = kp<K ? (f16)w[kp][n] : 0 ; wt row stride Kpad. block (32,8).
__global__ void tpad_kernel(const float* __restrict__ w, _Float16* __restrict__ wt,
                            int K, int Kpad, int N) {
    __shared__ float t[32][33];
    int k0 = blockIdx.x * 32, n0 = blockIdx.y * 32;
    int tx = threadIdx.x, ty = threadIdx.y;
    for (int i = ty; i < 32; i += 8) {
        int k = k0 + i;
        t[i][tx] = (k < K) ? w[(size_t)k * N + n0 + tx] : 0.f;
    }
    __syncthreads();
    for (int i = ty; i < 32; i += 8)
        wt[(size_t)(n0 + i) * Kpad + k0 + tx] = (_Float16)t[tx][i];
}

// blocks 0..2047: zero 8 MB H region WRITE-THROUGH; block 2048: zero sync words
__global__ void zero_kernel(char* __restrict__ p, unsigned* __restrict__ sync) {
    if (blockIdx.x == 2048) {
        if (threadIdx.x < 512)
            __hip_atomic_store(sync + threadIdx.x, 0u, __ATOMIC_RELAXED,
                               __HIP_MEMORY_SCOPE_AGENT);
        return;
    }
    u4v z = {0u, 0u, 0u, 0u};
    st16_wt(p + ((size_t)blockIdx.x * 256 + threadIdx.x) * 16, z);
}

// sync layout (u32 words): xcnt[g] g*16 | root 128 | epoch[g] 144+g*16 | flags 320..383
struct PArgs {
    const int* x;            // [1024][80]
    const _Float16* EMBP;    // [10000][128]
    const _Float16* W0XT;    // [1024][128]
    const _Float16* W0HT;    // [1024][1024]
    const _Float16* W1XT;    // [1024][1024]
    const _Float16* W1HT;    // [1024][1024]
    const float* b0; const float* b1;
    _Float16* H00; _Float16* H01;   // h0 ping-pong
    _Float16* H10; _Float16* H11;   // h1 ping-pong
    const float* wout; const float* bout; float* out;
    unsigned* sync;
    float* PS;               // 64 tiles x 128x128 f32 partials (l1 s1 halves)
};

// blocks 0..127 : l1 pairs — tile 128x128, s0 = h0@W1x, s1 = h1@W1h
// blocks 128..255: l0 — tile 128x64, K = EMBP(128) + h0(1024)
__launch_bounds__(512, 1)
__global__ void rnn_kernel(PArgs P) {
    __shared__ _Float16 As[4][128 * KC];   // 4 x 16 KB
    __shared__ _Float16 Bs[4][128 * KC];   // 4 x 16 KB (l0 uses half) -> 128 KB total

    const int tid  = threadIdx.x;
    const int lane = tid & 63, w = tid >> 6;   // 8 waves
    const int wr = w >> 1, wc = w & 1;          // wave tile grid 4x2
    const int quad = lane >> 4, l16 = lane & 15;
    const int b = blockIdx.x;
    const bool isL1 = b < 128;

    // A staging geometry (128 rows, 2 instrs/wave): g = w*2+q, rows [g*8, g*8+8)
    int rrA[2], gofA[2], arA[2];
    #pragma unroll
    for (int q = 0; q < 2; ++q) {
        int g = w * 2 + q;
        int r = g * 8 + (lane >> 3);
        rrA[q] = g * 512;                       // halves (8 rows x 64)
        gofA[q] = 8 * ((lane & 7) ^ (r & 7));   // XOR-8 swizzled k-offset
        arA[q] = r;
    }
    // B single-instr geometry (l0: 64 rows, 1 instr/wave)
    const int rB0 = w * 8 + (lane >> 3);
    const int rrB = w * 512;
    const int gofB = 8 * ((lane & 7) ^ (rB0 & 7));

    _Float16* Hh0[2] = { P.H00, P.H01 };
    _Float16* Hh1[2] = { P.H10, P.H11 };

    unsigned* xcnt  = P.sync + (b & 7) * 16;
    unsigned* root  = P.sync + 128;
    unsigned* epoch = P.sync + 144 + (b & 7) * 16;

    // ---- grid barrier: relaxed hierarchical (256 arrivals, 8 groups of 32) ----
    auto gsync = [&](unsigned tgt) {
        __syncthreads();                 // drains vmcnt(0): WT stores at coherent point
        if (tid == 0) {
            unsigned r = __hip_atomic_fetch_add(xcnt, 1u, __ATOMIC_RELAXED,
                                                __HIP_MEMORY_SCOPE_AGENT);
            if ((r & 31u) == 31u)
                __hip_atomic_fetch_add(root, 1u, __ATOMIC_RELAXED,
                                       __HIP_MEMORY_SCOPE_AGENT);
            if (b == 0) {
                while (__hip_atomic_load(root, __ATOMIC_RELAXED,
                                         __HIP_MEMORY_SCOPE_AGENT) < 8u * tgt)
                    __builtin_amdgcn_s_sleep(1);
                #pragma unroll
                for (int xx = 0; xx < 8; ++xx)
                    __hip_atomic_store(P.sync + 144 + xx * 16, tgt, __ATOMIC_RELAXED,
                                       __HIP_MEMORY_SCOPE_AGENT);
            }
            while (__hip_atomic_load(epoch, __ATOMIC_RELAXED,
                                     __HIP_MEMORY_SCOPE_AGENT) < tgt)
                __builtin_amdgcn_s_sleep(1);
        }
        __syncthreads();
    };

    if (isL1) {
        // decode: xcd=b&7, s=(b>>3)&1, hi=b>>4; tr=((hi>>2)<<2)|(xcd>>1),
        // tc=((hi&3)<<1)|(xcd&1)  -> pair (b, b+8) same tile; bijective over 64 tiles
        const int xcd = b & 7, s = (b >> 3) & 1, hi = b >> 4;
        const int tr = ((hi >> 2) << 2) | (xcd >> 1);
        const int tc = ((hi & 3) << 1) | (xcd & 1);
        const int row0 = tr * 128, col0 = tc * 128, tile = tr * 8 + tc;
        const _Float16* BW = s ? P.W1HT : P.W1XT;
        float* PSb = P.PS + (size_t)tile * 16384
                   + (size_t)(wr * 32 + quad * 4) * 128 + wc * 64 + l16;
        unsigned* flag = P.sync + 320 + tile;
        const _Float16* bp[2];
        #pragma unroll
        for (int q = 0; q < 2; ++q)
            bp[q] = BW + (size_t)(col0 + arA[q]) * UNITS + gofA[q];

        for (int it = 0; it <= SEQ; ++it) {
            const int p = it & 1;
            if (it >= 1) {
                const _Float16* aB = s ? Hh1[p] : Hh0[p ^ 1];
                const _Float16* ap[2];
                #pragma unroll
                for (int q = 0; q < 2; ++q)
                    ap[q] = aB + (size_t)(row0 + arA[q]) * UNITS + gofA[q];

                f4v acc[2][4] = {};
                auto iss = [&](int c) {
                    int buf = c & 3;
                    #pragma unroll
                    for (int q = 0; q < 2; ++q) {
                        gl_lds16_v(ap[q] + c * KC, &As[buf][0] + rrA[q]);
                        gl_lds16_c(bp[q] + c * KC, &Bs[buf][0] + rrA[q]);
                    }
                };
                iss(0); iss(1); iss(2);
                for (int c = 0; c < 16; ++c) {
                    const int cur = c & 3;
                    if (c + 3 < 16) iss(c + 3);
                    const int ahd = 15 - c;
                    if (ahd >= 3)      asm volatile("s_waitcnt vmcnt(12)" ::: "memory");
                    else if (ahd == 2) asm volatile("s_waitcnt vmcnt(8)"  ::: "memory");
                    else if (ahd == 1) asm volatile("s_waitcnt vmcnt(4)"  ::: "memory");
                    else               asm volatile("s_waitcnt vmcnt(0)"  ::: "memory");
                    __builtin_amdgcn_s_barrier();
                    __builtin_amdgcn_sched_barrier(0);
                    #pragma unroll
                    for (int kk = 0; kk < 2; ++kk) {
                        int us = 8 * ((kk * 4 + quad) ^ (l16 & 7));
                        h8v af[2], bf[4];
                        #pragma unroll
                        for (int i = 0; i < 2; ++i)
                            af[i] = *(const h8v*)(&As[cur][0] + (wr * 32 + i * 16 + l16) * KC + us);
                        #pragma unroll
                        for (int j = 0; j < 4; ++j)
                            bf[j] = *(const h8v*)(&Bs[cur][0] + (wc * 64 + j * 16 + l16) * KC + us);
                        #pragma unroll
                        for (int i = 0; i < 2; ++i)
                            #pragma unroll
                            for (int j = 0; j < 4; ++j)
                                acc[i][j] = __builtin_amdgcn_mfma_f32_16x16x32_f16(
                                    af[i], bf[j], acc[i][j], 0, 0, 0);
                    }
                    __builtin_amdgcn_sched_barrier(0);
                    __builtin_amdgcn_s_barrier();
                }

                if (s) {
                    // publish partial: WT f32 stores -> drain -> flag = it
                    #pragma unroll
                    for (int i = 0; i < 2; ++i)
                        #pragma unroll
                        for (int j = 0; j < 4; ++j)
                            #pragma unroll
                            for (int g = 0; g < 4; ++g)
                                st4_wt(PSb + (size_t)(i * 16 + g) * 128 + j * 16,
                                       acc[i][j][g]);
                    asm volatile("s_waitcnt vmcnt(0)" ::: "memory");
                    __syncthreads();     // all waves drained before the signal
                    if (tid == 0)
                        __hip_atomic_store(flag, (unsigned)it, __ATOMIC_RELAXED,
                                           __HIP_MEMORY_SCOPE_AGENT);
                } else {
                    // consume partner partial: poll flag, bypass-read, add, tanh
                    if (tid == 0) {
                        while (__hip_atomic_load(flag, __ATOMIC_RELAXED,
                                                 __HIP_MEMORY_SCOPE_AGENT) < (unsigned)it)
                            __builtin_amdgcn_s_sleep(1);
                    }
                    __syncthreads();
                    __builtin_amdgcn_sched_barrier(0);
                    float pv[2][4][4];
                    #pragma unroll
                    for (int i = 0; i < 2; ++i)
                        #pragma unroll
                        for (int j = 0; j < 4; ++j)
                            #pragma unroll
                            for (int g = 0; g < 4; ++g)
                                asm volatile("global_load_dword %0, %1, off sc0 sc1"
                                             : "=v"(pv[i][j][g])
                                             : "v"(PSb + (size_t)(i * 16 + g) * 128 + j * 16));
                    asm volatile("s_waitcnt vmcnt(0)" ::: "memory");
                    __builtin_amdgcn_sched_barrier(0);   // rule-18: pin pv uses below the drain
                    _Float16* outp = Hh1[p ^ 1];
                    #pragma unroll
                    for (int i = 0; i < 2; ++i) {
                        #pragma unroll
                        for (int j = 0; j < 4; ++j) {
                            int cc = col0 + wc * 64 + j * 16 + l16;
                            float bv = P.b1[cc];
                            #pragma unroll
                            for (int g = 0; g < 4; ++g) {
                                int r = row0 + wr * 32 + i * 16 + quad * 4 + g;
                                st2_wt(outp + (size_t)r * UNITS + cc,
                                       tanh_fast(acc[i][j][g] + pv[i][j][g] + bv));
                            }
                        }
                    }
                }
            }
            gsync((unsigned)(it + 1));
        }
    } else {
        // l0 decode: v bits -> tr=((v>>6)&1)<<2 | ((v>>1)&3), tc16=((v>>3)&7)<<1 | (v&1)
        const int v = b - 128;
        const int tr = (((v >> 6) & 1) << 2) | ((v >> 1) & 3);
        const int tc16 = (((v >> 3) & 7) << 1) | (v & 1);
        const int row0 = tr * 128, col0 = tc16 * 64;
        const _Float16* bxp = P.W0XT + (size_t)(col0 + rB0) * EPAD  + gofB;
        const _Float16* bhp = P.W0HT + (size_t)(col0 + rB0) * UNITS + gofB;

        for (int it = 0; it <= SEQ; ++it) {
            const int p = it & 1;
            if (it < SEQ) {
                const _Float16* ep[2]; const _Float16* ah[2];
                #pragma unroll
                for (int q = 0; q < 2; ++q) {
                    int xi = P.x[(size_t)(row0 + arA[q]) * SEQ + it];
                    ep[q] = P.EMBP + (size_t)xi * EPAD + gofA[q];
                    ah[q] = Hh0[p ^ 1] + (size_t)(row0 + arA[q]) * UNITS + gofA[q];
                }
                f4v acc[2][2] = {};
                auto iss = [&](int c) {
                    int buf = c & 3;
                    #pragma unroll
                    for (int q = 0; q < 2; ++q) {
                        if (c < 2) gl_lds16_c(ep[q] + c * KC, &As[buf][0] + rrA[q]);
                        else       gl_lds16_v(ah[q] + (c - 2) * KC, &As[buf][0] + rrA[q]);
                    }
                    if (c < 2) gl_lds16_c(bxp + c * KC, &Bs[buf][0] + rrB);
                    else       gl_lds16_c(bhp + (c - 2) * KC, &Bs[buf][0] + rrB);
                };
                iss(0); iss(1); iss(2);
                for (int c = 0; c < 18; ++c) {
                    const int cur = c & 3;
                    if (c + 3 < 18) iss(c + 3);
                    const int ahd = 17 - c;
                    if (ahd >= 3)      asm volatile("s_waitcnt vmcnt(9)" ::: "memory");
                    else if (ahd == 2) asm volatile("s_waitcnt vmcnt(6)" ::: "memory");
                    else if (ahd == 1) asm volatile("s_waitcnt vmcnt(3)" ::: "memory");
                    else               asm volatile("s_waitcnt vmcnt(0)" ::: "memory");
                    __builtin_amdgcn_s_barrier();
                    __builtin_amdgcn_sched_barrier(0);
                    #pragma unroll
                    for (int kk = 0; kk < 2; ++kk) {
                        int us = 8 * ((kk * 4 + quad) ^ (l16 & 7));
                        h8v af[2], bf[2];
                        #pragma unroll
                        for (int i = 0; i < 2; ++i)
                            af[i] = *(const h8v*)(&As[cur][0] + (wr * 32 + i * 16 + l16) * KC + us);
                        #pragma unroll
                        for (int j = 0; j < 2; ++j)
                            bf[j] = *(const h8v*)(&Bs[cur][0] + (wc * 32 + j * 16 + l16) * KC + us);
                        #pragma unroll
                        for (int i = 0; i < 2; ++i)
                            #pragma unroll
                            for (int j = 0; j < 2; ++j)
                                acc[i][j] = __builtin_amdgcn_mfma_f32_16x16x32_f16(
                                    af[i], bf[j], acc[i][j], 0, 0, 0);
                    }
                    __builtin_amdgcn_sched_barrier(0);
                    __builtin_amdgcn_s_barrier();
                }
                _Float16* outp = Hh0[p];
                #pragma unroll
                for (int i = 0; i < 2; ++i) {
                    #pragma unroll
                    for (int j = 0; j < 2; ++j) {
                        int cc = col0 + wc * 32 + j * 16 + l16;
                        float bv = P.b0[cc];
                        #pragma unroll
                        for (int g = 0; g < 4; ++g) {
                            int r = row0 + wr * 32 + i * 16 + quad * 4 + g;
                            st2_wt(outp + (size_t)r * UNITS + cc,
                                   tanh_fast(acc[i][j][g] + bv));
                        }
                    }
                }
            }
            gsync((unsigned)(it + 1));
        }
    }

    // tail: out[row] = sigmoid(h1_79[row] . wout + bout); h1_79 = H11 (bypass)
    if (b < 128) {
        int row = b * 8 + w;
        const _Float16* hr = P.H11 + (size_t)row * UNITS;
        u4v d0 = ld16_v(hr + lane * 16);
        u4v d1 = ld16_v(hr + lane * 16 + 8);
        float sacc = 0.f;
        #pragma unroll
        for (int i = 0; i < 4; ++i) {
            unsigned w0 = d0[i], w1 = d1[i];
            _Float16 h0 = __builtin_bit_cast(_Float16, (unsigned short)(w0 & 0xffffu));
            _Float16 h1 = __builtin_bit_cast(_Float16, (unsigned short)(w0 >> 16));
            _Float16 h2 = __builtin_bit_cast(_Float16, (unsigned short)(w1 & 0xffffu));
            _Float16 h3 = __builtin_bit_cast(_Float16, (unsigned short)(w1 >> 16));
            sacc += (float)h0 * P.wout[lane * 16 + 2 * i + 0];
            sacc += (float)h1 * P.wout[lane * 16 + 2 * i + 1];
            sacc += (float)h2 * P.wout[lane * 16 + 8 + 2 * i + 0];
            sacc += (float)h3 * P.wout[lane * 16 + 8 + 2 * i + 1];
        }
        #pragma unroll
        for (int off = 32; off; off >>= 1) sacc += __shfl_down(sacc, off);
        if (lane == 0)
            P.out[row] = 1.f / (1.f + __expf(-(sacc + P.bout[0])));
    }
}

extern "C" void kernel_launch(void* const* d_in, const int* in_sizes, int n_in,
                              void* d_out, int out_size, void* d_ws, size_t ws_size,
                              hipStream_t stream) {
    const int*   x    = (const int*)d_in[0];
    const float* emb  = (const float*)d_in[1];
    const float* W0x  = (const float*)d_in[2];
    const float* W0h  = (const float*)d_in[3];
    const float* b0   = (const float*)d_in[4];
    const float* W1x  = (const float*)d_in[5];
    const float* W1h  = (const float*)d_in[6];
    const float* b1   = (const float*)d_in[7];
    const float* Wout = (const float*)d_in[8];
    const float* bout = (const float*)d_in[9];
    float* out = (float*)d_out;

    char* ws = (char*)d_ws;
    _Float16* EMBP = (_Float16*)ws;                          // 2,560,000 B
    _Float16* W0XT = (_Float16*)(ws + 2560000);              // [1024][128]
    _Float16* W0HT = W0XT + 1024 * EPAD;                     // [1024][1024] x3
    _Float16* W1XT = W0HT + 1024 * 1024;
    _Float16* W1HT = W1XT + 1024 * 1024;
    _Float16* Hbuf = W1HT + 1024 * 1024;                     // 4 x 2 MB
    _Float16* H00 = Hbuf;
    _Float16* H01 = Hbuf + 1024 * 1024;
    _Float16* H10 = Hbuf + 2 * 1024 * 1024;
    _Float16* H11 = Hbuf + 3 * 1024 * 1024;
    unsigned* SYNC = (unsigned*)((char*)(Hbuf + 4 * 1024 * 1024));
    float* PS = (float*)((char*)SYNC + 4096);                // 64 x 16384 f32 = 4 MB

    embp_kernel<<<10000, EPAD, 0, stream>>>(emb, EMBP);
    tpad_kernel<<<dim3(4, 32),  dim3(32, 8), 0, stream>>>(W0x, W0XT, EMBD, EPAD, UNITS);
    tpad_kernel<<<dim3(32, 32), dim3(32, 8), 0, stream>>>(W0h, W0HT, UNITS, UNITS, UNITS);
    tpad_kernel<<<dim3(32, 32), dim3(32, 8), 0, stream>>>(W1x, W1XT, UNITS, UNITS, UNITS);
    tpad_kernel<<<dim3(32, 32), dim3(32, 8), 0, stream>>>(W1h, W1HT, UNITS, UNITS, UNITS);
    zero_kernel<<<2049, 256, 0, stream>>>((char*)Hbuf, SYNC); // WT zeros + sync+flags

    PArgs P;
    P.x = x; P.EMBP = EMBP;
    P.W0XT = W0XT; P.W0HT = W0HT; P.W1XT = W1XT; P.W1HT = W1HT;
    P.b0 = b0; P.b1 = b1;
    P.H00 = H00; P.H01 = H01; P.H10 = H10; P.H11 = H11;
    P.wout = Wout; P.bout = bout; P.out = out;
    P.sync = SYNC; P.PS = PS;
    rnn_kernel<<<GRID, 512, 0, stream>>>(P);
}

// Round 12
// 1679.740 us; speedup vs baseline: 1.2391x; 1.2391x over previous
//
#include <hip/hip_runtime.h>

// MyRnn: 2-layer SimpleRNN, B=1024 T=80 U=1024 E=100. f32 I/O, f16 MFMA compute.
// v10 (resubmit — R11 was a GPU-acquisition infra failure, no data):
// v7 VERBATIM except tile->block mapping. Evidence (v6-v9b): duration ==
// total EA (coherent-point) traffic / ~0.7-1.0 TB/s; per-CU staging-BW model
// refuted by v9b (halved staged bytes/CU -> slower, +10 MB/iter EA -> slower).
// Lever = unique EA bytes/iter. New mapping: XCD k (b&7==k, dispatch heuristic)
// owns rows [128k,128k+128) for BOTH layers -> h0/h1 row-windows are produced
// and consumed on the same XCD; unique bypass reads drop 11.25 -> ~6 MB/iter.
// Correctness does NOT depend on the mapping (WT sc0sc1 stores + bypass reads
// are device-coherent regardless; mapping is perf-only, G16-safe).
//   row0 = (b&7)*128 + ((b>>3)&1)*64 ; col0 = ((b>>4)&15)*64 ; z = b>>8 (as v7)

typedef _Float16 h8v __attribute__((ext_vector_type(8)));
typedef float    f4v __attribute__((ext_vector_type(4)));
typedef unsigned int u4v __attribute__((ext_vector_type(4)));

#define UNITS 1024
#define SEQ   80
#define EMBD  100
#define EPAD  128
#define KC    128
#define GRID  512

__device__ __forceinline__ float tanh_fast(float x) {
    x = fminf(15.f, fmaxf(-15.f, x));   // also scrubs NaN
    float e = __expf(2.f * x);
    return (e - 1.f) / (e + 1.f);
}

// cacheable global->LDS (weights, EMBP): L1/L2-resident across iterations
__device__ __forceinline__ void gl_lds16_c(const _Float16* g, _Float16* l) {
    __builtin_amdgcn_global_load_lds(
        (const __attribute__((address_space(1))) void*)g,
        (__attribute__((address_space(3))) void*)l, 16, 0, 0);
}
// device-coherent bypass global->LDS (h-state): aux = sc0|sc1 = 0x11
__device__ __forceinline__ void gl_lds16_v(const _Float16* g, _Float16* l) {
    __builtin_amdgcn_global_load_lds(
        (const __attribute__((address_space(1))) void*)g,
        (__attribute__((address_space(3))) void*)l, 16, 0, 0x11);
}
// write-through device-coherent 2B store (h-state)
__device__ __forceinline__ void st2_wt(_Float16* p, float v) {
    _Float16 h = (_Float16)v;
    unsigned int uv = (unsigned int)__builtin_bit_cast(unsigned short, h);
    asm volatile("global_store_short %0, %1, off sc0 sc1" :: "v"(p), "v"(uv) : "memory");
}
// device-coherent 16B load (tail h read)
__device__ __forceinline__ u4v ld16_v(const void* p) {
    u4v r;
    asm volatile("global_load_dwordx4 %0, %1, off sc0 sc1\n\ts_waitcnt vmcnt(0)"
                 : "=v"(r) : "v"(p) : "memory");
    return r;
}
// write-through 16B store (h zero-init must land at coherent point)
__device__ __forceinline__ void st16_wt(void* p, u4v v) {
    asm volatile("global_store_dwordx4 %0, %1, off sc0 sc1" :: "v"(p), "v"(v) : "memory");
}

// embp[r][k] = k<100 ? (f16)emb[r][k] : 0   (10000 x 128)
__global__ void embp_kernel(const float* __restrict__ emb, _Float16* __restrict__ embp) {
    int r = blockIdx.x, k = threadIdx.x;
    embp[r * EPAD + k] = (k < EMBD) ? (_Float16)emb[r * EMBD + k] : (_Float16)0.f;
}

// wt[n][kp] = kp<K ? (f16)w[kp][n] : 0 ; wt row stride Kpad. block (32,8).
__global__ void tpad_kernel(const float* __restrict__ w, _Float16* __restrict__ wt,
                            int K, int Kpad, int N) {
    __shared__ float t[32][33];
    int k0 = blockIdx.x * 32, n0 = blockIdx.y * 32;
    int tx = threadIdx.x, ty = threadIdx.y;
    for (int i = ty; i < 32; i += 8) {
        int k = k0 + i;
        t[i][tx] = (k < K) ? w[(size_t)k * N + n0 + tx] : 0.f;
    }
    __syncthreads();
    for (int i = ty; i < 32; i += 8)
        wt[(size_t)(n0 + i) * Kpad + k0 + tx] = (_Float16)t[tx][i];
}

// blocks 0..2047: zero 8 MB H region WRITE-THROUGH; block 2048: zero sync words
__global__ void zero_kernel(char* __restrict__ p, unsigned* __restrict__ sync) {
    if (blockIdx.x == 2048) {
        if (threadIdx.x < 512)
            __hip_atomic_store(sync + threadIdx.x, 0u, __ATOMIC_RELAXED,
                               __HIP_MEMORY_SCOPE_AGENT);
        return;
    }
    u4v z = {0u, 0u, 0u, 0u};
    st16_wt(p + ((size_t)blockIdx.x * 256 + threadIdx.x) * 16, z);
}

// sync layout (u32 words): xcnt[g] at [g*16], root at [128], epoch[g] at [144+g*16]
struct PArgs {
    const int* x;            // [1024][80]
    const _Float16* EMBP;    // [10000][128]
    const _Float16* W0XT;    // [1024][128]
    const _Float16* W0HT;    // [1024][1024]
    const _Float16* W1XT;    // [1024][1024]
    const _Float16* W1HT;    // [1024][1024]
    const float* b0; const float* b1;
    _Float16* H00; _Float16* H01;   // h0 ping-pong
    _Float16* H10; _Float16* H11;   // h1 ping-pong
    const float* wout; const float* bout; float* out;
    unsigned* sync;
};

// z = 0 (blocks 0..255):   l1 task — h1_{it-1} = tanh(h0_{it-1}@W1x + h1_{it-2}@W1h + b1), it in [1,80]
// z = 1 (blocks 256..511): l0 task — h0_{it}   = tanh(emb[x[:,it]]@W0x + h0_{it-1}@W0h + b0), it in [0,79]
__launch_bounds__(256, 2)
__global__ void rnn_kernel(PArgs P) {
    __shared__ _Float16 As[2][64 * KC];   // 2 x 16 KB, XOR-8 swizzled
    __shared__ _Float16 Bs[2][64 * KC];   // 2 x 16 KB  (total 64 KB -> 2 blocks/CU)

    const int tid  = threadIdx.x;
    const int lane = tid & 63, w = tid >> 6;
    const int wm = w >> 1, wn = w & 1;
    const int quad = lane >> 4, l16 = lane & 15;

    const int b   = blockIdx.x;          // 0..511
    const int z   = b >> 8;              // task select
    // v10 ROW-LOCAL mapping: XCD k = b&7 owns rows [128k, 128k+128) for BOTH
    // tasks -> h row-windows produced & consumed on one XCD (perf-only).
    const int row0 = (b & 7) * 128 + ((b >> 3) & 1) * 64;
    const int col0 = ((b >> 4) & 15) * 64;

    // staging geometry: wave-instr g = w*4+q covers rows [g*4, g*4+4), lane l ->
    // row r = g*4 + (l>>4), stored unit u' = l&15, logical unit u = u' ^ (r&7)
    int rr[4], goff[4], arow[4];
    #pragma unroll
    for (int q = 0; q < 4; ++q) {
        int g = w * 4 + q;
        int r = g * 4 + (lane >> 4);
        rr[q]   = g * 512;                        // LDS base (halves)
        goff[q] = 8 * ((lane & 15) ^ (r & 7));    // swizzled k-offset (halves)
        arow[q] = r;
    }

    // iteration-invariant B (weight) panel pointers — cacheable, L2-hot
    const _Float16* B0T = z ? P.W0XT : P.W1XT;
    const _Float16* B1T = z ? P.W0HT : P.W1HT;
    const int  ldb0  = z ? EPAD : UNITS;
    const int  nch0_ = z ? 1 : 8;
    const int  nch_  = nch0_ + 8;
    const float* bias = z ? P.b0 : P.b1;
    const _Float16* b0p[4]; const _Float16* b1p[4];
    #pragma unroll
    for (int q = 0; q < 4; ++q) {
        b0p[q] = B0T + (size_t)(col0 + arow[q]) * ldb0  + goff[q];
        b1p[q] = B1T + (size_t)(col0 + arow[q]) * UNITS + goff[q];
    }

    _Float16* Hh0[2] = { P.H00, P.H01 };
    _Float16* Hh1[2] = { P.H10, P.H11 };

    unsigned* xcnt  = P.sync + (b & 7) * 16;
    unsigned* root  = P.sync + 128;
    unsigned* epoch = P.sync + 144 + (b & 7) * 16;

    for (int it = 0; it <= SEQ; ++it) {
        const int p = it & 1;
        const bool active = z ? (it < SEQ) : (it >= 1);
        if (active) {
            const _Float16* a0p[4]; const _Float16* a1p[4];
            _Float16* outp;
            if (z) {                      // l0: out h0_it
                outp = Hh0[p];
                const _Float16* a1b = Hh0[p ^ 1];
                #pragma unroll
                for (int q = 0; q < 4; ++q) {
                    int xi = P.x[(size_t)(row0 + arow[q]) * SEQ + it];
                    a0p[q] = P.EMBP + (size_t)xi * EPAD + goff[q];
                    a1p[q] = a1b + (size_t)(row0 + arow[q]) * UNITS + goff[q];
                }
            } else {                      // l1: out h1_{it-1}
                outp = Hh1[p ^ 1];
                const _Float16* a0b = Hh0[p ^ 1];
                const _Float16* a1b = Hh1[p];
                #pragma unroll
                for (int q = 0; q < 4; ++q) {
                    a0p[q] = a0b + (size_t)(row0 + arow[q]) * UNITS + goff[q];
                    a1p[q] = a1b + (size_t)(row0 + arow[q]) * UNITS + goff[q];
                }
            }

            f4v acc[2][2] = {};

            // A-side: h-state panels bypass (always for l1; source-1 for l0);
            // EMBP (l0 source-0) cacheable. B-side (weights) always cacheable.
            auto issue = [&](int c, int buf) {
                #pragma unroll
                for (int q = 0; q < 4; ++q) {
                    const _Float16* ap; const _Float16* bp; bool byp;
                    if (c < nch0_) { ap = a0p[q] + c * KC; bp = b0p[q] + c * KC; byp = (z == 0); }
                    else { int cc = c - nch0_; ap = a1p[q] + cc * KC; bp = b1p[q] + cc * KC; byp = true; }
                    if (byp) gl_lds16_v(ap, &As[buf][0] + rr[q]);
                    else     gl_lds16_c(ap, &As[buf][0] + rr[q]);
                    gl_lds16_c(bp, &Bs[buf][0] + rr[q]);
                }
            };

            issue(0, 0);
            for (int c = 0; c < nch_; ++c) {
                const int cur = c & 1;
                if (c + 1 < nch_) {
                    issue(c + 1, cur ^ 1);                        // next chunk in flight
                    asm volatile("s_waitcnt vmcnt(8)" ::: "memory");   // my chunk-c landed
                } else {
                    asm volatile("s_waitcnt vmcnt(0)" ::: "memory");
                }
                __builtin_amdgcn_s_barrier();
                __builtin_amdgcn_sched_barrier(0);
                #pragma unroll
                for (int kk = 0; kk < 4; ++kk) {
                    int us = 8 * ((kk * 4 + quad) ^ (l16 & 7));
                    h8v af[2], bf[2];
                    #pragma unroll
                    for (int i = 0; i < 2; ++i)
                        af[i] = *(const h8v*)(&As[cur][0] + (wm * 32 + i * 16 + l16) * KC + us);
                    #pragma unroll
                    for (int j = 0; j < 2; ++j)
                        bf[j] = *(const h8v*)(&Bs[cur][0] + (wn * 32 + j * 16 + l16) * KC + us);
                    #pragma unroll
                    for (int i = 0; i < 2; ++i)
                        #pragma unroll
                        for (int j = 0; j < 2; ++j)
                            acc[i][j] = __builtin_amdgcn_mfma_f32_16x16x32_f16(
                                af[i], bf[j], acc[i][j], 0, 0, 0);
                }
                __builtin_amdgcn_sched_barrier(0);
                __builtin_amdgcn_s_barrier();
            }

            // epilogue: write-through device-coherent h stores (no dirty L2 lines)
            #pragma unroll
            for (int i = 0; i < 2; ++i) {
                int r = row0 + wm * 32 + i * 16 + quad * 4;
                #pragma unroll
                for (int j = 0; j < 2; ++j) {
                    int cc = col0 + wn * 32 + j * 16 + l16;
                    float bv = bias[cc];
                    #pragma unroll
                    for (int g = 0; g < 4; ++g)
                        st2_wt(outp + (size_t)(r + g) * UNITS + cc,
                               tanh_fast(acc[i][j][g] + bv));
                }
            }
        }

        // ---- grid barrier: relaxed atomics only (no inv, no wbl2) ----
        // __syncthreads drains vmcnt(0): all WT h-stores are at the coherent
        // point before the arrival FAA becomes visible.
        const unsigned tgt = (unsigned)(it + 1);
        __syncthreads();
        if (tid == 0) {
            unsigned r = __hip_atomic_fetch_add(xcnt, 1u, __ATOMIC_RELAXED,
                                                __HIP_MEMORY_SCOPE_AGENT);
            if ((r & 63u) == 63u)        // group complete -> promote to root
                __hip_atomic_fetch_add(root, 1u, __ATOMIC_RELAXED,
                                       __HIP_MEMORY_SCOPE_AGENT);
            if (b == 0) {
                while (__hip_atomic_load(root, __ATOMIC_RELAXED,
                                         __HIP_MEMORY_SCOPE_AGENT) < 8u * tgt)
                    __builtin_amdgcn_s_sleep(8);
                #pragma unroll
                for (int xx = 0; xx < 8; ++xx)
                    __hip_atomic_store(P.sync + 144 + xx * 16, tgt, __ATOMIC_RELAXED,
                                       __HIP_MEMORY_SCOPE_AGENT);
            }
            while (__hip_atomic_load(epoch, __ATOMIC_RELAXED,
                                     __HIP_MEMORY_SCOPE_AGENT) < tgt)
                __builtin_amdgcn_s_sleep(2);
        }
        __syncthreads();
    }

    // tail: out[b] = sigmoid(h1_79[b] . wout + bout); h1_79 = H11 (bypass reads)
    if (b < 256) {
        int row = b * 4 + (tid >> 6);
        const _Float16* hr = P.H11 + (size_t)row * UNITS;
        u4v d0 = ld16_v(hr + lane * 16);
        u4v d1 = ld16_v(hr + lane * 16 + 8);
        float sacc = 0.f;
        #pragma unroll
        for (int i = 0; i < 4; ++i) {
            unsigned w0 = d0[i], w1 = d1[i];
            _Float16 h0 = __builtin_bit_cast(_Float16, (unsigned short)(w0 & 0xffffu));
            _Float16 h1 = __builtin_bit_cast(_Float16, (unsigned short)(w0 >> 16));
            _Float16 h2 = __builtin_bit_cast(_Float16, (unsigned short)(w1 & 0xffffu));
            _Float16 h3 = __builtin_bit_cast(_Float16, (unsigned short)(w1 >> 16));
            sacc += (float)h0 * P.wout[lane * 16 + 2 * i + 0];
            sacc += (float)h1 * P.wout[lane * 16 + 2 * i + 1];
            sacc += (float)h2 * P.wout[lane * 16 + 8 + 2 * i + 0];
            sacc += (float)h3 * P.wout[lane * 16 + 8 + 2 * i + 1];
        }
        #pragma unroll
        for (int off = 32; off; off >>= 1) sacc += __shfl_down(sacc, off);
        if (lane == 0)
            P.out[row] = 1.f / (1.f + __expf(-(sacc + P.bout[0])));
    }
}

extern "C" void kernel_launch(void* const* d_in, const int* in_sizes, int n_in,
                              void* d_out, int out_size, void* d_ws, size_t ws_size,
                              hipStream_t stream) {
    const int*   x    = (const int*)d_in[0];
    const float* emb  = (const float*)d_in[1];
    const float* W0x  = (const float*)d_in[2];
    const float* W0h  = (const float*)d_in[3];
    const float* b0   = (const float*)d_in[4];
    const float* W1x  = (const float*)d_in[5];
    const float* W1h  = (const float*)d_in[6];
    const float* b1   = (const float*)d_in[7];
    const float* Wout = (const float*)d_in[8];
    const float* bout = (const float*)d_in[9];
    float* out = (float*)d_out;

    char* ws = (char*)d_ws;
    _Float16* EMBP = (_Float16*)ws;                          // 10000*128*2 = 2,560,000 B
    _Float16* W0XT = (_Float16*)(ws + 2560000);              // [1024][128]  = 262,144 B
    _Float16* W0HT = W0XT + 1024 * EPAD;                     // [1024][1024] x3
    _Float16* W1XT = W0HT + 1024 * 1024;
    _Float16* W1HT = W1XT + 1024 * 1024;
    _Float16* Hbuf = W1HT + 1024 * 1024;                     // 4 x 2 MB
    _Float16* H00 = Hbuf;
    _Float16* H01 = Hbuf + 1024 * 1024;
    _Float16* H10 = Hbuf + 2 * 1024 * 1024;
    _Float16* H11 = Hbuf + 3 * 1024 * 1024;
    unsigned* SYNC = (unsigned*)((char*)(Hbuf + 4 * 1024 * 1024));

    embp_kernel<<<10000, EPAD, 0, stream>>>(emb, EMBP);
    tpad_kernel<<<dim3(4, 32),  dim3(32, 8), 0, stream>>>(W0x, W0XT, EMBD, EPAD, UNITS);
    tpad_kernel<<<dim3(32, 32), dim3(32, 8), 0, stream>>>(W0h, W0HT, UNITS, UNITS, UNITS);
    tpad_kernel<<<dim3(32, 32), dim3(32, 8), 0, stream>>>(W1x, W1XT, UNITS, UNITS, UNITS);
    tpad_kernel<<<dim3(32, 32), dim3(32, 8), 0, stream>>>(W1h, W1HT, UNITS, UNITS, UNITS);
    zero_kernel<<<2049, 256, 0, stream>>>((char*)Hbuf, SYNC); // WT zeros + sync words

    PArgs P;
    P.x = x; P.EMBP = EMBP;
    P.W0XT = W0XT; P.W0HT = W0HT; P.W1XT = W1XT; P.W1HT = W1HT;
    P.b0 = b0; P.b1 = b1;
    P.H00 = H00; P.H01 = H01; P.H10 = H10; P.H11 = H11;
    P.wout = Wout; P.bout = bout; P.out = out;
    P.sync = SYNC;
    rnn_kernel<<<GRID, 256, 0, stream>>>(P);
}